// Round 11
// baseline (820.465 us; speedup 1.0000x reference)
//
#include <hip/hip_runtime.h>

#define A3 180
#define A2 128
#define W2D 384
#define NV 192
#define NU 256
#define VZ 192
#define VY 192
#define VX 192

// cone-BP tile geometry: 32x8 tile, 8 z per thread -> 3456 blocks (13.5/CU)
// for full wave residency; per-block window v-span <= ~15 << 32 staged rows.
#define BX 32
#define BY 8
#define CZPT 8
#define WROWS 32       // v window rows (live span <= ~15)
#define WDW 64         // u window cols (live span <= ~49 incl. margins+align)

// bp2d tile geometry: 32u x 32v -> per-angle pos span = 31(|c|+|s|) <= 44
#define BU2 32
#define BV2 32
#define VPT2 4
#define PW 64          // staged cols per angle (max rel tap 47 < 64)

static constexpr double PI_D = 3.14159265358979323846;

// async global->LDS; dest = wave-uniform base + lane*size
#define GLOAD16(gaddr, laddr)                                                    \
    __builtin_amdgcn_global_load_lds(                                            \
        (const __attribute__((address_space(1))) unsigned int*)(gaddr),          \
        (__attribute__((address_space(3))) unsigned int*)(laddr), 16, 0, 0)
#define GLOAD4(gaddr, laddr)                                                     \
    __builtin_amdgcn_global_load_lds(                                            \
        (const __attribute__((address_space(1))) unsigned int*)(gaddr),          \
        (__attribute__((address_space(3))) unsigned int*)(laddr), 4, 0, 0)

// ---------------- Kernel T: trig tables ----------------
__global__ void tables_kernel(float* __restrict__ c2, float* __restrict__ s2,
                              float* __restrict__ cbt, float* __restrict__ sbt) {
    int i = threadIdx.x;
    if (i < A2) {
        float th = (float)i * (float)(PI_D / A2);
        c2[i] = cosf(th);
        s2[i] = sinf(th);
    }
    if (i < A3) {
        float be = (float)i * (float)(2.0 * PI_D / A3);
        cbt[i] = cosf(be);
        sbt[i] = sinf(be);
    }
}

// ---------------- Kernel A: d = grad_last(sino * weight) ----------------
__global__ __launch_bounds__(W2D) void grad_kernel(const float* __restrict__ sino,
                                                   const float* __restrict__ wini,
                                                   float* __restrict__ d) {
    __shared__ float p[W2D];
    size_t base = (size_t)blockIdx.x * W2D;
    int w = threadIdx.x;
    p[w] = sino[base + w] * wini[base + w];
    __syncthreads();
    float g;
    if (w == 0)            g = p[1] - p[0];
    else if (w == W2D - 1) g = p[W2D - 1] - p[W2D - 2];
    else                   g = (p[w + 1] - p[w - 1]) * 0.5f;
    d[base + w] = g;
}

// ---------------- Kernel B: 2D parallel BP + cosine weight (LDS window) ----
// Tile 32u x 32v. pos linear in (u,v) -> tile min exact at a corner. Tile
// span 31(|c|+|s|) <= 43.9; margin 2 + tap -> max rel index 47 < PW=64.
__global__ __launch_bounds__(256) void bp2d_kernel(const float* __restrict__ d,
                                                   const float* __restrict__ c2,
                                                   const float* __restrict__ s2,
                                                   float* __restrict__ wcb) {
    __shared__ float rowwin[2][4][PW];
    __shared__ float csl[A2], ssl[A2];
    __shared__ int umin_s[A2];

    int tid = threadIdx.x;
    int ul = tid & 31;
    int vth = tid >> 5;
    int wv = tid >> 6;
    int lane = tid & 63;
    int u0g = blockIdx.x * BU2;
    int v0g = blockIdx.y * BV2;
    int a3 = blockIdx.z;

    float uf = (float)(u0g + ul) - 127.5f;
    float vf0 = (float)(v0g + vth * VPT2) - 95.5f;
    const float* slab = d + (size_t)a3 * (A2 * W2D);

    if (tid < A2) {
        float c = c2[tid], s = s2[tid];
        csl[tid] = c; ssl[tid] = s;
        float cu0 = ((float)u0g - 127.5f) * c;
        float cu1 = ((float)(u0g + BU2 - 1) - 127.5f) * c;
        float cv0 = ((float)v0g - 95.5f) * s;
        float cv1 = ((float)(v0g + BV2 - 1) - 95.5f) * s;
        float m = fminf(cu0, cu1) + fminf(cv0, cv1) + 191.5f;
        umin_s[tid] = (int)m - 2;
    }
    __syncthreads();

    {
        int um = umin_s[wv];
        int colg = min(um + lane, W2D - 1);
        GLOAD4(slab + wv * W2D + colg, &rowwin[0][wv][0]);
    }
    __syncthreads();

    float acc[VPT2];
#pragma unroll
    for (int k = 0; k < VPT2; ++k) acc[k] = 0.0f;

    for (int g = 0; g < A2 / 4; ++g) {
        int buf = g & 1;
        if (g + 1 < A2 / 4) {
            int aa = (g + 1) * 4 + wv;
            int um = umin_s[aa];
            int colg = min(um + lane, W2D - 1);
            GLOAD4(slab + aa * W2D + colg, &rowwin[buf ^ 1][wv][0]);
        }
#pragma unroll
        for (int j = 0; j < 4; ++j) {
            int aa = g * 4 + j;
            float c = csl[aa], s = ssl[aa];
            float pb = fmaf(uf, c, fmaf(vf0, s, 191.5f - (float)umin_s[aa]));
            const float* rw = rowwin[buf][j];
#pragma unroll
            for (int k = 0; k < VPT2; ++k) {
                float pos = fmaf((float)k, s, pb);
                int i0 = (int)pos;
                float f = __builtin_amdgcn_fractf(pos);
                float r0 = rw[i0], r1 = rw[i0 + 1];
                acc[k] = fmaf(f, r1 - r0, acc[k] + r0);
            }
        }
        __syncthreads();
    }

    float x = uf * 2.0f;
    float scale = (float)((PI_D / A2) * (2.0 * PI_D / A3));
#pragma unroll
    for (int k = 0; k < VPT2; ++k) {
        float y = (vf0 + (float)k) * 2.0f;
        float w3 = 1200.0f * __builtin_amdgcn_rsqf(1440000.0f + x * x + y * y);
        int v = v0g + vth * VPT2 + k;
        wcb[((size_t)a3 * NV + v) * NU + u0g + ul] = acc[k] * scale * w3;
    }
}

// ---------------- Kernel C: cone-beam BP ----------------
// 32x8 voxel tile, 8 z per thread (3456 blocks -> full residency). Window
// origins from block corners (Moebius-monotone -> corner-attained min),
// clamped so the 64x32 window is statically inside wcb; staging = 2 width-16
// global_load_lds per wave per beta, double-buffered, one barrier per beta.
__global__ __launch_bounds__(256, 8) void conebp_kernel(const float* __restrict__ wcb,
                                                        const float* __restrict__ cbt,
                                                        const float* __restrict__ sbt,
                                                        float* __restrict__ out) {
    __shared__ float win[2][WROWS * WDW];   // 16 KB
    __shared__ int orgs_s[A3 + 2];

    int tid = threadIdx.x;
    int tx = tid & (BX - 1);
    int ty = tid >> 5;
    int wid = tid >> 6;
    int lane = tid & 63;

    int x = blockIdx.x * BX + tx;
    int y = blockIdx.y * BY + ty;
    int z0 = blockIdx.z * CZPT;

    float xf = (float)x - 95.5f;
    float yf = (float)y - 95.5f;
    float z0f = (float)z0 - 95.5f;

    // ---- one-time: per-beta window origins from block corners ----
    {
        float cxf0 = (float)(blockIdx.x * BX) - 95.5f;
        float cxf1 = cxf0 + (float)(BX - 1);
        float cyf0 = (float)(blockIdx.y * BY) - 95.5f;
        float cyf1 = cyf0 + (float)(BY - 1);
        if (tid < A3) {
            float cbb = cbt[tid], sbb = sbt[tid];
            float iumin = 1e30f, ivmin = 1e30f;
#pragma unroll
            for (int c = 0; c < 4; ++c) {
                float cx = (c & 1) ? cxf1 : cxf0;
                float cy = (c & 2) ? cyf1 : cyf0;
                float rr = cx * cbb + cy * sbb;
                float inv = __builtin_amdgcn_rcpf(750.0f - rr);
                float tt = cy * cbb - cx * sbb;
                iumin = fminf(iumin, fmaf(600.0f * tt, inv, 135.5f));
                ivmin = fminf(ivmin, fmaf(600.0f * z0f, inv, 95.5f));
            }
            int um = (int)iumin - 9;              // floor -8 bias -1 margin
            um = min(max(um, 0), 192) & ~3;       // 16B-aligned, in-bounds
            int vm = min(max((int)ivmin - 1, 1), 160);
            orgs_s[tid] = (vm << 16) | um;
        }
        if (tid >= A3 && tid < A3 + 2) orgs_s[tid] = (1 << 16);
    }
    __syncthreads();

    float acc[CZPT];
#pragma unroll
    for (int k = 0; k < CZPT; ++k) acc[k] = 0.0f;

    // per-lane staging offset (dwords) in GLOBAL window layout:
    // row = wid*4 + (lane>>4), col = 4*(lane&15); global row stride 256.
    unsigned pre = ((unsigned)(lane >> 4) << 8) + ((unsigned)(lane & 15) << 2)
                 + ((unsigned)wid << 10);
    float* const win0 = &win[0][0];
    float* const win1 = &win[1][0];

    int orgc = orgs_s[0];
    int orgn = orgs_s[1];
    {   // prologue: stage beta 0 into win[0]
        unsigned umin = orgc & 0xffffu, vmin = (unsigned)orgc >> 16;
        const float* src = wcb + (vmin << 8) + umin + pre;
        float* dst = win0 + ((unsigned)wid << 8);
        GLOAD16(src, dst);
        GLOAD16(src + 4096, dst + 1024);
    }
    __syncthreads();

    for (int a = 0; a < A3; ++a) {
        int cur = a & 1;

        if (a + 1 < A3) {   // stage next beta into alternate buffer (async)
            unsigned umin = orgn & 0xffffu, vmin = (unsigned)orgn >> 16;
            const float* src = wcb + (size_t)(a + 1) * (NV * NU)
                             + (vmin << 8) + umin + pre;
            float* dst = (cur ? win0 : win1) + ((unsigned)wid << 8);
            GLOAD16(src, dst);
            GLOAD16(src + 4096, dst + 1024);
        }

        float cb = cbt[a], sb = sbt[a];
        float r = fmaf(xf, cb, yf * sb);
        float t = fmaf(yf, cb, -xf * sb);
        float inv = __builtin_amdgcn_rcpf(750.0f - r);
        float iub = fmaf(600.0f * t, inv, 135.5f);   // +8 bias, > 0
        int u0 = (int)iub - 8;
        float fu = __builtin_amdgcn_fractf(iub);
        float wgt = 750.0f * inv;
        wgt *= wgt;                                   // (DSO/denom)^2
        float wa = ((unsigned)u0 < NU) ? (1.0f - fu) * wgt : 0.0f;
        float wb = ((unsigned)(u0 + 1) < NU) ? fu * wgt : 0.0f;
        float dstep = 600.0f * inv;

        unsigned uminc = orgc & 0xffffu, vminc = (unsigned)orgc >> 16;
        float ivr = fmaf(dstep, z0f, 95.5f - (float)vminc);   // window-rel >= 1
        const float* w0 = (cur ? win1 : win0) + (u0 - (int)uminc);

#pragma unroll
        for (int k = 0; k < CZPT; ++k) {
            float iv = fmaf((float)k, dstep, ivr);
            int v0 = (int)iv;                         // trunc == floor
            float fv = __builtin_amdgcn_fractf(iv);
            int o = v0 << 6;                          // window stride 64
            float p00 = w0[o], p01 = w0[o + 1];
            float p10 = w0[o + WDW], p11 = w0[o + WDW + 1];
            float q0 = fmaf(fv, p10 - p00, p00);
            float q1 = fmaf(fv, p11 - p01, p01);
            acc[k] = fmaf(wa, q0, acc[k]);
            acc[k] = fmaf(wb, q1, acc[k]);
        }

        __syncthreads();   // drains async staging + protects buffer swap
        orgc = orgn;
        orgn = orgs_s[a + 2];
    }

#pragma unroll
    for (int k = 0; k < CZPT; ++k) {
        out[(((size_t)(z0 + k)) * VY + y) * VX + x] = acc[k];
    }
}

extern "C" void kernel_launch(void* const* d_in, const int* in_sizes, int n_in,
                              void* d_out, int out_size, void* d_ws, size_t ws_size,
                              hipStream_t stream) {
    const float* sino = (const float*)d_in[0];  // [1,1,A3,A2,W2D] flat
    const float* wini = (const float*)d_in[1];  // [A3,A2,W2D] flat
    float* out = (float*)d_out;                 // [1,VZ,VY,VX] flat

    float* d   = (float*)d_ws;                        // A3*A2*W2D
    float* wcb = d + (size_t)A3 * A2 * W2D;           // A3*NV*NU
    float* c2  = wcb + (size_t)A3 * NV * NU;
    float* s2  = c2 + A2;
    float* cbt = s2 + A2;
    float* sbt = cbt + A3;

    tables_kernel<<<1, 256, 0, stream>>>(c2, s2, cbt, sbt);
    grad_kernel<<<A3 * A2, W2D, 0, stream>>>(sino, wini, d);
    bp2d_kernel<<<dim3(NU / BU2, NV / BV2, A3), 256, 0, stream>>>(d, c2, s2, wcb);
    conebp_kernel<<<dim3(VX / BX, VY / BY, VZ / CZPT), 256, 0, stream>>>(wcb, cbt, sbt, out);
}

// Round 12
// 757.446 us; speedup vs baseline: 1.0832x; 1.0832x over previous
//
#include <hip/hip_runtime.h>

#define A3 180
#define A2 128
#define W2D 384
#define NV 192
#define NU 256
#define VZ 192
#define VY 192
#define VX 192

// cone-BP tile geometry: 32x8 tile, 12 z per thread -> 2304 blocks (9/CU).
#define BX 32
#define BY 8
#define CZPT 12
#define WROWS 32       // v window rows (live span <= ~19)
#define WDW 64         // u window cols (live span <= ~49 incl. margins+align)

// bp2d tile geometry: 32u x 32v -> per-angle pos span = 31(|c|+|s|) <= 44
#define BU2 32
#define BV2 32
#define VPT2 4
#define PW 64          // staged cols per angle (max rel tap 47 < 64)

static constexpr double PI_D = 3.14159265358979323846;

typedef float f32x2 __attribute__((ext_vector_type(2)));

// async global->LDS; dest = wave-uniform base + lane*size
#define GLOAD16(gaddr, laddr)                                                    \
    __builtin_amdgcn_global_load_lds(                                            \
        (const __attribute__((address_space(1))) unsigned int*)(gaddr),          \
        (__attribute__((address_space(3))) unsigned int*)(laddr), 16, 0, 0)
#define GLOAD4(gaddr, laddr)                                                     \
    __builtin_amdgcn_global_load_lds(                                            \
        (const __attribute__((address_space(1))) unsigned int*)(gaddr),          \
        (__attribute__((address_space(3))) unsigned int*)(laddr), 4, 0, 0)

// ---------------- Kernel T: trig tables ----------------
__global__ void tables_kernel(float* __restrict__ c2, float* __restrict__ s2,
                              float* __restrict__ cbt, float* __restrict__ sbt) {
    int i = threadIdx.x;
    if (i < A2) {
        float th = (float)i * (float)(PI_D / A2);
        c2[i] = cosf(th);
        s2[i] = sinf(th);
    }
    if (i < A3) {
        float be = (float)i * (float)(2.0 * PI_D / A3);
        cbt[i] = cosf(be);
        sbt[i] = sinf(be);
    }
}

// ---------------- Kernel A: d = grad_last(sino * weight) ----------------
__global__ __launch_bounds__(W2D) void grad_kernel(const float* __restrict__ sino,
                                                   const float* __restrict__ wini,
                                                   float* __restrict__ d) {
    __shared__ float p[W2D];
    size_t base = (size_t)blockIdx.x * W2D;
    int w = threadIdx.x;
    p[w] = sino[base + w] * wini[base + w];
    __syncthreads();
    float g;
    if (w == 0)            g = p[1] - p[0];
    else if (w == W2D - 1) g = p[W2D - 1] - p[W2D - 2];
    else                   g = (p[w + 1] - p[w - 1]) * 0.5f;
    d[base + w] = g;
}

// ---------------- Kernel B: 2D parallel BP + cosine weight (LDS window) ----
__global__ __launch_bounds__(256) void bp2d_kernel(const float* __restrict__ d,
                                                   const float* __restrict__ c2,
                                                   const float* __restrict__ s2,
                                                   float* __restrict__ wcb) {
    __shared__ float rowwin[2][4][PW];
    __shared__ float csl[A2], ssl[A2];
    __shared__ int umin_s[A2];

    int tid = threadIdx.x;
    int ul = tid & 31;
    int vth = tid >> 5;
    int wv = tid >> 6;
    int lane = tid & 63;
    int u0g = blockIdx.x * BU2;
    int v0g = blockIdx.y * BV2;
    int a3 = blockIdx.z;

    float uf = (float)(u0g + ul) - 127.5f;
    float vf0 = (float)(v0g + vth * VPT2) - 95.5f;
    const float* slab = d + (size_t)a3 * (A2 * W2D);

    if (tid < A2) {
        float c = c2[tid], s = s2[tid];
        csl[tid] = c; ssl[tid] = s;
        float cu0 = ((float)u0g - 127.5f) * c;
        float cu1 = ((float)(u0g + BU2 - 1) - 127.5f) * c;
        float cv0 = ((float)v0g - 95.5f) * s;
        float cv1 = ((float)(v0g + BV2 - 1) - 95.5f) * s;
        float m = fminf(cu0, cu1) + fminf(cv0, cv1) + 191.5f;
        umin_s[tid] = (int)m - 2;
    }
    __syncthreads();

    {
        int um = umin_s[wv];
        int colg = min(um + lane, W2D - 1);
        GLOAD4(slab + wv * W2D + colg, &rowwin[0][wv][0]);
    }
    __syncthreads();

    float acc[VPT2];
#pragma unroll
    for (int k = 0; k < VPT2; ++k) acc[k] = 0.0f;

    for (int g = 0; g < A2 / 4; ++g) {
        int buf = g & 1;
        if (g + 1 < A2 / 4) {
            int aa = (g + 1) * 4 + wv;
            int um = umin_s[aa];
            int colg = min(um + lane, W2D - 1);
            GLOAD4(slab + aa * W2D + colg, &rowwin[buf ^ 1][wv][0]);
        }
#pragma unroll
        for (int j = 0; j < 4; ++j) {
            int aa = g * 4 + j;
            float c = csl[aa], s = ssl[aa];
            float pb = fmaf(uf, c, fmaf(vf0, s, 191.5f - (float)umin_s[aa]));
            const float* rw = rowwin[buf][j];
#pragma unroll
            for (int k = 0; k < VPT2; ++k) {
                float pos = fmaf((float)k, s, pb);
                int i0 = (int)pos;
                float f = __builtin_amdgcn_fractf(pos);
                float r0 = rw[i0], r1 = rw[i0 + 1];
                acc[k] = fmaf(f, r1 - r0, acc[k] + r0);
            }
        }
        __syncthreads();
    }

    float x = uf * 2.0f;
    float scale = (float)((PI_D / A2) * (2.0 * PI_D / A3));
#pragma unroll
    for (int k = 0; k < VPT2; ++k) {
        float y = (vf0 + (float)k) * 2.0f;
        float w3 = 1200.0f * __builtin_amdgcn_rsqf(1440000.0f + x * x + y * y);
        int v = v0g + vth * VPT2 + k;
        wcb[((size_t)a3 * NV + v) * NU + u0g + ul] = acc[k] * scale * w3;
    }
}

// ---------------- Kernel C: cone-beam BP ----------------
// 32x8 voxel tile, 12 z per thread (2304 blocks). Window origins from block
// corners; 64x32 window statically inside wcb; staging = 2 width-16
// global_load_lds per wave per beta, double-buffered, one barrier per beta.
// z-loop FLOPs in packed f32 (v_pk_fma_f32): q=(q0,q1) lerped packed, acc2
// accumulates (wa*q0, wb*q1) packed, halves summed once at the end.
__global__ __launch_bounds__(256, 8) void conebp_kernel(const float* __restrict__ wcb,
                                                        const float* __restrict__ cbt,
                                                        const float* __restrict__ sbt,
                                                        float* __restrict__ out) {
    __shared__ float win[2][WROWS * WDW];   // 16 KB
    __shared__ int orgs_s[A3 + 2];

    int tid = threadIdx.x;
    int tx = tid & (BX - 1);
    int ty = tid >> 5;
    int wid = tid >> 6;
    int lane = tid & 63;

    int x = blockIdx.x * BX + tx;
    int y = blockIdx.y * BY + ty;
    int z0 = blockIdx.z * CZPT;

    float xf = (float)x - 95.5f;
    float yf = (float)y - 95.5f;
    float z0f = (float)z0 - 95.5f;

    // ---- one-time: per-beta window origins from block corners ----
    {
        float cxf0 = (float)(blockIdx.x * BX) - 95.5f;
        float cxf1 = cxf0 + (float)(BX - 1);
        float cyf0 = (float)(blockIdx.y * BY) - 95.5f;
        float cyf1 = cyf0 + (float)(BY - 1);
        if (tid < A3) {
            float cbb = cbt[tid], sbb = sbt[tid];
            float iumin = 1e30f, ivmin = 1e30f;
#pragma unroll
            for (int c = 0; c < 4; ++c) {
                float cx = (c & 1) ? cxf1 : cxf0;
                float cy = (c & 2) ? cyf1 : cyf0;
                float rr = cx * cbb + cy * sbb;
                float inv = __builtin_amdgcn_rcpf(750.0f - rr);
                float tt = cy * cbb - cx * sbb;
                iumin = fminf(iumin, fmaf(600.0f * tt, inv, 135.5f));
                ivmin = fminf(ivmin, fmaf(600.0f * z0f, inv, 95.5f));
            }
            int um = (int)iumin - 9;              // floor -8 bias -1 margin
            um = min(max(um, 0), 192) & ~3;       // 16B-aligned, in-bounds
            int vm = min(max((int)ivmin - 1, 1), 160);
            orgs_s[tid] = (vm << 16) | um;
        }
        if (tid >= A3 && tid < A3 + 2) orgs_s[tid] = (1 << 16);
    }
    __syncthreads();

    f32x2 acc2[CZPT];
#pragma unroll
    for (int k = 0; k < CZPT; ++k) acc2[k] = (f32x2)0.0f;

    // per-lane staging offset (dwords) in GLOBAL window layout:
    // row = wid*4 + (lane>>4), col = 4*(lane&15); global row stride 256.
    unsigned pre = ((unsigned)(lane >> 4) << 8) + ((unsigned)(lane & 15) << 2)
                 + ((unsigned)wid << 10);
    float* const win0 = &win[0][0];
    float* const win1 = &win[1][0];

    int orgc = orgs_s[0];
    int orgn = orgs_s[1];
    {   // prologue: stage beta 0 into win[0]
        unsigned umin = orgc & 0xffffu, vmin = (unsigned)orgc >> 16;
        const float* src = wcb + (vmin << 8) + umin + pre;
        float* dst = win0 + ((unsigned)wid << 8);
        GLOAD16(src, dst);
        GLOAD16(src + 4096, dst + 1024);
    }
    __syncthreads();

    for (int a = 0; a < A3; ++a) {
        int cur = a & 1;

        if (a + 1 < A3) {   // stage next beta into alternate buffer (async)
            unsigned umin = orgn & 0xffffu, vmin = (unsigned)orgn >> 16;
            const float* src = wcb + (size_t)(a + 1) * (NV * NU)
                             + (vmin << 8) + umin + pre;
            float* dst = (cur ? win0 : win1) + ((unsigned)wid << 8);
            GLOAD16(src, dst);
            GLOAD16(src + 4096, dst + 1024);
        }

        float cb = cbt[a], sb = sbt[a];
        float r = fmaf(xf, cb, yf * sb);
        float t = fmaf(yf, cb, -xf * sb);
        float inv = __builtin_amdgcn_rcpf(750.0f - r);
        float iub = fmaf(600.0f * t, inv, 135.5f);   // +8 bias, > 0
        int u0 = (int)iub - 8;
        float fu = __builtin_amdgcn_fractf(iub);
        float wgt = 750.0f * inv;
        wgt *= wgt;                                   // (DSO/denom)^2
        float wa = ((unsigned)u0 < NU) ? (1.0f - fu) * wgt : 0.0f;
        float wb = ((unsigned)(u0 + 1) < NU) ? fu * wgt : 0.0f;
        f32x2 wab; wab.x = wa; wab.y = wb;
        float dstep = 600.0f * inv;

        unsigned uminc = orgc & 0xffffu, vminc = (unsigned)orgc >> 16;
        float ivr = fmaf(dstep, z0f, 95.5f - (float)vminc);   // window-rel >= 1
        const float* w0 = (cur ? win1 : win0) + (u0 - (int)uminc);

#pragma unroll
        for (int k = 0; k < CZPT; ++k) {
            float iv = fmaf((float)k, dstep, ivr);
            int v0 = (int)iv;                         // trunc == floor
            float fv = __builtin_amdgcn_fractf(iv);
            int o = v0 << 6;                          // window stride 64
            f32x2 p0; p0.x = w0[o];       p0.y = w0[o + 1];
            f32x2 p1; p1.x = w0[o + WDW]; p1.y = w0[o + WDW + 1];
            f32x2 fv2; fv2.x = fv; fv2.y = fv;
            f32x2 q = __builtin_elementwise_fma(fv2, p1 - p0, p0);
            acc2[k] = __builtin_elementwise_fma(wab, q, acc2[k]);
        }

        __syncthreads();   // drains async staging + protects buffer swap
        orgc = orgn;
        orgn = orgs_s[a + 2];
    }

#pragma unroll
    for (int k = 0; k < CZPT; ++k) {
        out[(((size_t)(z0 + k)) * VY + y) * VX + x] = acc2[k].x + acc2[k].y;
    }
}

extern "C" void kernel_launch(void* const* d_in, const int* in_sizes, int n_in,
                              void* d_out, int out_size, void* d_ws, size_t ws_size,
                              hipStream_t stream) {
    const float* sino = (const float*)d_in[0];  // [1,1,A3,A2,W2D] flat
    const float* wini = (const float*)d_in[1];  // [A3,A2,W2D] flat
    float* out = (float*)d_out;                 // [1,VZ,VY,VX] flat

    float* d   = (float*)d_ws;                        // A3*A2*W2D
    float* wcb = d + (size_t)A3 * A2 * W2D;           // A3*NV*NU
    float* c2  = wcb + (size_t)A3 * NV * NU;
    float* s2  = c2 + A2;
    float* cbt = s2 + A2;
    float* sbt = cbt + A3;

    tables_kernel<<<1, 256, 0, stream>>>(c2, s2, cbt, sbt);
    grad_kernel<<<A3 * A2, W2D, 0, stream>>>(sino, wini, d);
    bp2d_kernel<<<dim3(NU / BU2, NV / BV2, A3), 256, 0, stream>>>(d, c2, s2, wcb);
    conebp_kernel<<<dim3(VX / BX, VY / BY, VZ / CZPT), 256, 0, stream>>>(wcb, cbt, sbt, out);
}

// Round 13
// 734.957 us; speedup vs baseline: 1.1163x; 1.0306x over previous
//
#include <hip/hip_runtime.h>

#define A3 180
#define A2 128
#define W2D 384
#define NV 192
#define NU 256
#define VZ 192
#define VY 192
#define VX 192

// cone-BP tile geometry: 32x8 tile, 12 z per thread -> 2304 blocks (9/CU).
#define BX 32
#define BY 8
#define CZPT 12
#define WROWS 20       // v window rows (live span <= ~18.6)
#define WDW 64         // u window cols (live span <= ~49 incl. margins+align)

// bp2d tile geometry: 32u x 32v -> per-angle pos span = 31(|c|+|s|) <= 44
#define BU2 32
#define BV2 32
#define VPT2 4
#define PW 64          // staged cols per angle (max rel tap 47 < 64)

static constexpr double PI_D = 3.14159265358979323846;

typedef float f32x2 __attribute__((ext_vector_type(2)));

// async global->LDS; dest = wave-uniform base + lane*size
#define GLOAD16(gaddr, laddr)                                                    \
    __builtin_amdgcn_global_load_lds(                                            \
        (const __attribute__((address_space(1))) unsigned int*)(gaddr),          \
        (__attribute__((address_space(3))) unsigned int*)(laddr), 16, 0, 0)
#define GLOAD4(gaddr, laddr)                                                     \
    __builtin_amdgcn_global_load_lds(                                            \
        (const __attribute__((address_space(1))) unsigned int*)(gaddr),          \
        (__attribute__((address_space(3))) unsigned int*)(laddr), 4, 0, 0)

// ---------------- Kernel T: trig tables ----------------
__global__ void tables_kernel(float* __restrict__ c2, float* __restrict__ s2,
                              float* __restrict__ cbt, float* __restrict__ sbt) {
    int i = threadIdx.x;
    if (i < A2) {
        float th = (float)i * (float)(PI_D / A2);
        c2[i] = cosf(th);
        s2[i] = sinf(th);
    }
    if (i < A3) {
        float be = (float)i * (float)(2.0 * PI_D / A3);
        cbt[i] = cosf(be);
        sbt[i] = sinf(be);
    }
}

// ---------------- Kernel A: d = grad_last(sino * weight) ----------------
__global__ __launch_bounds__(W2D) void grad_kernel(const float* __restrict__ sino,
                                                   const float* __restrict__ wini,
                                                   float* __restrict__ d) {
    __shared__ float p[W2D];
    size_t base = (size_t)blockIdx.x * W2D;
    int w = threadIdx.x;
    p[w] = sino[base + w] * wini[base + w];
    __syncthreads();
    float g;
    if (w == 0)            g = p[1] - p[0];
    else if (w == W2D - 1) g = p[W2D - 1] - p[W2D - 2];
    else                   g = (p[w + 1] - p[w - 1]) * 0.5f;
    d[base + w] = g;
}

// ---------------- Kernel B: 2D parallel BP + cosine weight (LDS window) ----
__global__ __launch_bounds__(256) void bp2d_kernel(const float* __restrict__ d,
                                                   const float* __restrict__ c2,
                                                   const float* __restrict__ s2,
                                                   float* __restrict__ wcb) {
    __shared__ float rowwin[2][4][PW];
    __shared__ float csl[A2], ssl[A2];
    __shared__ int umin_s[A2];

    int tid = threadIdx.x;
    int ul = tid & 31;
    int vth = tid >> 5;
    int wv = tid >> 6;
    int lane = tid & 63;
    int u0g = blockIdx.x * BU2;
    int v0g = blockIdx.y * BV2;
    int a3 = blockIdx.z;

    float uf = (float)(u0g + ul) - 127.5f;
    float vf0 = (float)(v0g + vth * VPT2) - 95.5f;
    const float* slab = d + (size_t)a3 * (A2 * W2D);

    if (tid < A2) {
        float c = c2[tid], s = s2[tid];
        csl[tid] = c; ssl[tid] = s;
        float cu0 = ((float)u0g - 127.5f) * c;
        float cu1 = ((float)(u0g + BU2 - 1) - 127.5f) * c;
        float cv0 = ((float)v0g - 95.5f) * s;
        float cv1 = ((float)(v0g + BV2 - 1) - 95.5f) * s;
        float m = fminf(cu0, cu1) + fminf(cv0, cv1) + 191.5f;
        umin_s[tid] = (int)m - 2;
    }
    __syncthreads();

    {
        int um = umin_s[wv];
        int colg = min(um + lane, W2D - 1);
        GLOAD4(slab + wv * W2D + colg, &rowwin[0][wv][0]);
    }
    __syncthreads();

    float acc[VPT2];
#pragma unroll
    for (int k = 0; k < VPT2; ++k) acc[k] = 0.0f;

    for (int g = 0; g < A2 / 4; ++g) {
        int buf = g & 1;
        if (g + 1 < A2 / 4) {
            int aa = (g + 1) * 4 + wv;
            int um = umin_s[aa];
            int colg = min(um + lane, W2D - 1);
            GLOAD4(slab + aa * W2D + colg, &rowwin[buf ^ 1][wv][0]);
        }
#pragma unroll
        for (int j = 0; j < 4; ++j) {
            int aa = g * 4 + j;
            float c = csl[aa], s = ssl[aa];
            float pb = fmaf(uf, c, fmaf(vf0, s, 191.5f - (float)umin_s[aa]));
            const float* rw = rowwin[buf][j];
#pragma unroll
            for (int k = 0; k < VPT2; ++k) {
                float pos = fmaf((float)k, s, pb);
                int i0 = (int)pos;
                float f = __builtin_amdgcn_fractf(pos);
                float r0 = rw[i0], r1 = rw[i0 + 1];
                acc[k] = fmaf(f, r1 - r0, acc[k] + r0);
            }
        }
        __syncthreads();
    }

    float x = uf * 2.0f;
    float scale = (float)((PI_D / A2) * (2.0 * PI_D / A3));
#pragma unroll
    for (int k = 0; k < VPT2; ++k) {
        float y = (vf0 + (float)k) * 2.0f;
        float w3 = 1200.0f * __builtin_amdgcn_rsqf(1440000.0f + x * x + y * y);
        int v = v0g + vth * VPT2 + k;
        wcb[((size_t)a3 * NV + v) * NU + u0g + ul] = acc[k] * scale * w3;
    }
}

// ---------------- Kernel C: cone-beam BP ----------------
// 32x8 voxel tile, 12 z per thread. 4 LDS windows (20x64 each): betas are
// processed in PAIRS; while computing pair p (2 betas), pair p+1's windows
// stream in via global_load_lds -> ONE barrier per 2 betas (90 total), each
// drain hidden under 24 z-iterations of compute. Packed-f32 tap math.
__global__ __launch_bounds__(256, 8) void conebp_kernel(const float* __restrict__ wcb,
                                                        const float* __restrict__ cbt,
                                                        const float* __restrict__ sbt,
                                                        float* __restrict__ out) {
    __shared__ float win[4][WROWS * WDW];   // 20 KB
    __shared__ int orgs_s[A3];

    int tid = threadIdx.x;
    int tx = tid & (BX - 1);
    int ty = tid >> 5;
    int wid = tid >> 6;
    int lane = tid & 63;

    int x = blockIdx.x * BX + tx;
    int y = blockIdx.y * BY + ty;
    int z0 = blockIdx.z * CZPT;

    float xf = (float)x - 95.5f;
    float yf = (float)y - 95.5f;
    float z0f = (float)z0 - 95.5f;

    // ---- one-time: per-beta window origins from block corners ----
    {
        float cxf0 = (float)(blockIdx.x * BX) - 95.5f;
        float cxf1 = cxf0 + (float)(BX - 1);
        float cyf0 = (float)(blockIdx.y * BY) - 95.5f;
        float cyf1 = cyf0 + (float)(BY - 1);
        if (tid < A3) {
            float cbb = cbt[tid], sbb = sbt[tid];
            float iumin = 1e30f, ivmin = 1e30f;
#pragma unroll
            for (int c = 0; c < 4; ++c) {
                float cx = (c & 1) ? cxf1 : cxf0;
                float cy = (c & 2) ? cyf1 : cyf0;
                float rr = cx * cbb + cy * sbb;
                float inv = __builtin_amdgcn_rcpf(750.0f - rr);
                float tt = cy * cbb - cx * sbb;
                iumin = fminf(iumin, fmaf(600.0f * tt, inv, 135.5f));
                ivmin = fminf(ivmin, fmaf(600.0f * z0f, inv, 95.5f));
            }
            int um = (int)iumin - 9;              // floor -8 bias -1 margin
            um = min(max(um, 0), 192) & ~3;       // 16B-aligned, in-bounds
            int vm = min(max((int)ivmin - 1, 1), 172);  // +19 rows stays < 192
            orgs_s[tid] = (vm << 16) | um;
        }
    }
    __syncthreads();

    f32x2 acc2[CZPT];
#pragma unroll
    for (int k = 0; k < CZPT; ++k) acc2[k] = (f32x2)0.0f;

    // per-lane staging offset (dwords) in GLOBAL window layout:
    // row = wid*4 + (lane>>4), col = 4*(lane&15); global row stride 256.
    unsigned pre = ((unsigned)(lane >> 4) << 8) + ((unsigned)(lane & 15) << 2)
                 + ((unsigned)wid << 10);

    // stage beta b's 20x64 window into win[buf]: rows 0-15 all waves,
    // rows 16-19 wave 0 only.
    auto stage = [&](int b, int buf) {
        int org = orgs_s[b];
        unsigned umin = org & 0xffffu, vmin = (unsigned)org >> 16;
        const float* src = wcb + (size_t)b * (NV * NU) + (vmin << 8) + umin;
        float* dst = &win[buf][0];
        GLOAD16(src + pre, dst + ((unsigned)wid << 8));
        if (wid == 0)
            GLOAD16(src + 4096 + pre, dst + 1024);   // rows 16..19
    };

    // compute beta b from window win[buf]
    auto compute = [&](int b, int buf) {
        float cb = cbt[b], sb = sbt[b];
        float r = fmaf(xf, cb, yf * sb);
        float t = fmaf(yf, cb, -xf * sb);
        float inv = __builtin_amdgcn_rcpf(750.0f - r);
        float iub = fmaf(600.0f * t, inv, 135.5f);   // +8 bias, > 0
        int u0 = (int)iub - 8;
        float fu = __builtin_amdgcn_fractf(iub);
        float wgt = 750.0f * inv;
        wgt *= wgt;                                   // (DSO/denom)^2
        float wa = ((unsigned)u0 < NU) ? (1.0f - fu) * wgt : 0.0f;
        float wb = ((unsigned)(u0 + 1) < NU) ? fu * wgt : 0.0f;
        f32x2 wab; wab.x = wa; wab.y = wb;
        float dstep = 600.0f * inv;

        int org = orgs_s[b];
        unsigned uminc = org & 0xffffu, vminc = (unsigned)org >> 16;
        float ivr = fmaf(dstep, z0f, 95.5f - (float)vminc);   // window-rel >= 1
        const float* w0 = &win[buf][0] + (u0 - (int)uminc);

#pragma unroll
        for (int k = 0; k < CZPT; ++k) {
            float iv = fmaf((float)k, dstep, ivr);
            int v0 = (int)iv;                         // trunc == floor
            float fv = __builtin_amdgcn_fractf(iv);
            int o = v0 << 6;                          // window stride 64
            f32x2 p0; p0.x = w0[o];       p0.y = w0[o + 1];
            f32x2 p1; p1.x = w0[o + WDW]; p1.y = w0[o + WDW + 1];
            f32x2 fv2; fv2.x = fv; fv2.y = fv;
            f32x2 q = __builtin_elementwise_fma(fv2, p1 - p0, p0);
            acc2[k] = __builtin_elementwise_fma(wab, q, acc2[k]);
        }
    };

    // prologue: stage pair 0
    stage(0, 0);
    stage(1, 1);
    __syncthreads();

    for (int p = 0; p < A3 / 2; ++p) {
        int cur = (p & 1) << 1;          // 0 or 2
        if (p + 1 < A3 / 2) {
            stage(2 * p + 2, cur ^ 2);
            stage(2 * p + 3, (cur ^ 2) + 1);
        }
        compute(2 * p,     cur);
        compute(2 * p + 1, cur + 1);
        __syncthreads();   // drains async staging of pair p+1
    }

#pragma unroll
    for (int k = 0; k < CZPT; ++k) {
        out[(((size_t)(z0 + k)) * VY + y) * VX + x] = acc2[k].x + acc2[k].y;
    }
}

extern "C" void kernel_launch(void* const* d_in, const int* in_sizes, int n_in,
                              void* d_out, int out_size, void* d_ws, size_t ws_size,
                              hipStream_t stream) {
    const float* sino = (const float*)d_in[0];  // [1,1,A3,A2,W2D] flat
    const float* wini = (const float*)d_in[1];  // [A3,A2,W2D] flat
    float* out = (float*)d_out;                 // [1,VZ,VY,VX] flat

    float* d   = (float*)d_ws;                        // A3*A2*W2D
    float* wcb = d + (size_t)A3 * A2 * W2D;           // A3*NV*NU
    float* c2  = wcb + (size_t)A3 * NV * NU;
    float* s2  = c2 + A2;
    float* cbt = s2 + A2;
    float* sbt = cbt + A3;

    tables_kernel<<<1, 256, 0, stream>>>(c2, s2, cbt, sbt);
    grad_kernel<<<A3 * A2, W2D, 0, stream>>>(sino, wini, d);
    bp2d_kernel<<<dim3(NU / BU2, NV / BV2, A3), 256, 0, stream>>>(d, c2, s2, wcb);
    conebp_kernel<<<dim3(VX / BX, VY / BY, VZ / CZPT), 256, 0, stream>>>(wcb, cbt, sbt, out);
}